// Round 6
// baseline (599.891 us; speedup 1.0000x reference)
//
#include <hip/hip_runtime.h>
#include <math.h>

#define B_ 32
#define F_ 128
#define H_ 256
#define N_ 2048
#define L_ 2
#define E_ 262144
#define NN_ 65536          // B_*N_
// DEG = E/(B*N) = 4

typedef __attribute__((ext_vector_type(8))) short short8;   // 8 bf16 = 4 VGPRs (MFMA A/B frag)
typedef __attribute__((ext_vector_type(4))) float f32x4;    // MFMA C/D frag

static __device__ __forceinline__ unsigned short f2bf(float f) {
  unsigned int u = __float_as_uint(f);
  u += 0x7FFF + ((u >> 16) & 1);      // round-to-nearest-even
  return (unsigned short)(u >> 16);
}
static __device__ __forceinline__ float bf2f(unsigned short u) {
  return __uint_as_float(((unsigned int)u) << 16);
}

// ---------------- small kernels ----------------

__global__ void h0_kernel(const float* __restrict__ x, const float* __restrict__ W_in,
                          const float* __restrict__ b_in, float* __restrict__ h0) {
  int b = blockIdx.x;
  int j = threadIdx.x;
  float acc = b_in[j];
#pragma unroll 8
  for (int k = 0; k < F_; ++k)
    acc += x[b * F_ + k] * W_in[k * H_ + j];
  h0[b * H_ + j] = acc;
}

__global__ void meand_kernel(const float* __restrict__ positions, float* __restrict__ mean_d) {
  __shared__ float red[256];
  int i = blockIdx.x;
  int t = threadIdx.x;
  float px = positions[i * 3 + 0], py = positions[i * 3 + 1], pz = positions[i * 3 + 2];
  float s = 0.f;
  for (int j = t; j < N_; j += 256) {
    float dx = px - positions[j * 3 + 0];
    float dy = py - positions[j * 3 + 1];
    float dz = pz - positions[j * 3 + 2];
    s += sqrtf(dx * dx + dy * dy + dz * dz);
  }
  red[t] = s;
  __syncthreads();
  for (int off = 128; off > 0; off >>= 1) {
    if (t < off) red[t] += red[t + off];
    __syncthreads();
  }
  if (t == 0) mean_d[i] = red[0] / (float)(N_ - 1);
}

__global__ void g_kernel(const float* __restrict__ mean_d,
                         const float* __restrict__ Wg1, const float* __restrict__ bg1,
                         const float* __restrict__ Wg2, const float* __restrict__ bg2,
                         float* __restrict__ g) {
  __shared__ float hid[128];
  int n = blockIdx.x;
  int t = threadIdx.x;
  float md = mean_d[n];
  if (t < 128) {
    float w = Wg1[t] + Wg1[128 + t] + Wg1[256 + t];
    hid[t] = fmaxf(md * w + bg1[t], 0.f);
  }
  __syncthreads();
  float acc = bg2[t];
#pragma unroll 8
  for (int k = 0; k < 128; ++k)
    acc += hid[k] * Wg2[k * H_ + t];
  g[n * H_ + t] = acc;
}

__global__ void hinit_kernel(const float* __restrict__ h0, const float* __restrict__ g,
                             float* __restrict__ h) {
  int idx = blockIdx.x * blockDim.x + threadIdx.x;
  int row = idx >> 6;
  int c4 = (idx & 63) << 2;
  const float4 a = *(const float4*)(h0 + (row >> 11) * H_ + c4);
  const float4 b = *(const float4*)(g + (row & (N_ - 1)) * H_ + c4);
  float4 r;
  r.x = a.x + b.x; r.y = a.y + b.y; r.z = a.z + b.z; r.w = a.w + b.w;
  *(float4*)(h + row * H_ + c4) = r;
}

__global__ void posinit_kernel(const float* __restrict__ positions, float* __restrict__ pos) {
  int i = blockIdx.x * blockDim.x + threadIdx.x;
  int row = i / 3;
  int c = i - row * 3;
  pos[i] = positions[(row & (N_ - 1)) * 3 + c];
}

__global__ void out_kernel(const float* __restrict__ h, const float* __restrict__ Wout,
                           const float* __restrict__ bout, float* __restrict__ out) {
  int gid = blockIdx.x * blockDim.x + threadIdx.x;
  int node = gid >> 6;
  int lane = gid & 63;
  const float4 hv = *(const float4*)(h + node * H_ + (lane << 2));
  const float4 wv = *(const float4*)(Wout + (lane << 2));
  float p = hv.x * wv.x + hv.y * wv.y + hv.z * wv.z + hv.w * wv.w;
#pragma unroll
  for (int m = 1; m < 64; m <<= 1) p += __shfl_xor(p, m, 64);
  if (lane == 0) out[node] = p + bout[0];
}

// ---------------- CSR build (counting sort of edges by dst) ----------------

__global__ void deg_kernel(const int* __restrict__ ei, int* __restrict__ deg) {
  int e = blockIdx.x * 256 + threadIdx.x;
  atomicAdd(&deg[ei[E_ + e]], 1);
}

__global__ void scan1_kernel(const int* __restrict__ deg, int* __restrict__ bsum) {
  __shared__ int red[256];
  int t = threadIdx.x;
  red[t] = deg[blockIdx.x * 256 + t];
  __syncthreads();
  for (int off = 128; off > 0; off >>= 1) {
    if (t < off) red[t] += red[t + off];
    __syncthreads();
  }
  if (t == 0) bsum[blockIdx.x] = red[0];
}

__global__ void scan2_kernel(int* __restrict__ bsum) {
  __shared__ int s[256];
  int t = threadIdx.x;
  s[t] = bsum[t];
  __syncthreads();
  for (int off = 1; off < 256; off <<= 1) {
    int v = (t >= off) ? s[t - off] : 0;
    __syncthreads();
    s[t] += v;
    __syncthreads();
  }
  bsum[t] = (t == 0) ? 0 : s[t - 1];
}

__global__ void scan3_kernel(const int* __restrict__ deg, const int* __restrict__ bsum,
                             int* __restrict__ cur) {
  __shared__ int s[256];
  int t = threadIdx.x;
  int i = blockIdx.x * 256 + t;
  s[t] = deg[i];
  __syncthreads();
  for (int off = 1; off < 256; off <<= 1) {
    int v = (t >= off) ? s[t - off] : 0;
    __syncthreads();
    s[t] += v;
    __syncthreads();
  }
  int excl = (t == 0) ? 0 : s[t - 1];
  cur[i] = bsum[blockIdx.x] + excl;
}

// scatter src indices into dst-sorted order
__global__ void scatter_kernel(const int* __restrict__ ei, int* __restrict__ cur,
                               int* __restrict__ src_s) {
  int e = blockIdx.x * 256 + threadIdx.x;
  int s = ei[e], d = ei[E_ + e];
  int p = atomicAdd(&cur[d], 1);
  src_s[p] = s;
}

// ---------------- weight conversion (FRAGMENT-ORDER layout) ----------------
// B-frag for MFMA 16x16x32: lane (q,r) of wave w, col-tile ni, k-step (kc,ks):
//   element n = w*64 + ni*16 + r, k = kc*64 + ks*32 + q*8 + j  (j=0..7)
// Layout: [kc][w][ks][ni][lane] x 8 shorts -> one coalesced 1KB dwordx4 load/wave.

// Wu [512][256] -> WutF (16384 frag-groups of 8)
__global__ void wconvU_kernel(const float* __restrict__ W, unsigned short* __restrict__ Wt) {
  int idx = blockIdx.x * 256 + threadIdx.x;    // 0..16383
  int kc = idx >> 11;
  int w  = (idx >> 9) & 3;
  int ks = (idx >> 8) & 1;
  int ni = (idx >> 6) & 3;
  int lane = idx & 63;
  int r = lane & 15, q = lane >> 4;
  int n  = (w << 6) + (ni << 4) + r;
  int kb = (kc << 6) + (ks << 5) + (q << 3);
  unsigned short* dst = Wt + ((size_t)idx << 3);
#pragma unroll
  for (int j = 0; j < 8; ++j)
    dst[j] = f2bf(W[(size_t)(kb + j) * H_ + n]);
}

// Wm [513][256]: top 256 rows (g=0) and bottom 256 rows (g=1) -> frag-order [g][kc=0..3][w][ks][ni][lane]
__global__ void wconvM_kernel(const float* __restrict__ Wm, unsigned short* __restrict__ Wt) {
  int idx = blockIdx.x * 256 + threadIdx.x;    // 0..16383
  int g = idx >> 13;
  int rem = idx & 8191;
  int kc = rem >> 11;
  int w  = (rem >> 9) & 3;
  int ks = (rem >> 8) & 1;
  int ni = (rem >> 6) & 3;
  int lane = rem & 63;
  int r = lane & 15, q = lane >> 4;
  int n  = (w << 6) + (ni << 4) + r;
  int kb = (g << 8) + (kc << 6) + (ks << 5) + (q << 3);
  unsigned short* dst = Wt + ((size_t)idx << 3);
#pragma unroll
  for (int j = 0; j < 8; ++j)
    dst[j] = f2bf(Wm[(size_t)(kb + j) * H_ + n]);
}

__global__ void hbf_kernel(const float* __restrict__ h, unsigned short* __restrict__ hbf) {
  int i = (blockIdx.x * blockDim.x + threadIdx.x) << 3;
  const float4 a = *(const float4*)(h + i);
  const float4 b = *(const float4*)(h + i + 4);
  short8 v;
  v[0] = (short)f2bf(a.x); v[1] = (short)f2bf(a.y);
  v[2] = (short)f2bf(a.z); v[3] = (short)f2bf(a.w);
  v[4] = (short)f2bf(b.x); v[5] = (short)f2bf(b.y);
  v[6] = (short)f2bf(b.z); v[7] = (short)f2bf(b.w);
  *(short8*)(hbf + i) = v;
}

// ---------------- GEMM1 (LDS-free): X = hbf@WmTop (bf16), Zb = hbf@WmBot + bm (bf16) ----------------
// grid (NN/64, 2): y=0 -> X, y=1 -> Zb. 64 rows x 256 cols per block, K=256.
// A-frags and B-frags loaded directly from global (L1/L2-served); no barriers.
__launch_bounds__(256)
__global__ void gemm1_mfma(const unsigned short* __restrict__ hbf,
                           const unsigned short* __restrict__ Wt,   // frag-order [g][4][4][2][4][64]x8
                           const float* __restrict__ bm,
                           unsigned short* __restrict__ X, unsigned short* __restrict__ Zb) {
  const int t = threadIdx.x;
  const int m0 = blockIdx.x << 6;
  const int g = blockIdx.y;
  const int w = t >> 6;
  const int lane = t & 63;
  const int q = lane >> 4;
  const int r = lane & 15;

  f32x4 acc[4][4];
#pragma unroll
  for (int mi = 0; mi < 4; ++mi)
#pragma unroll
    for (int ni = 0; ni < 4; ++ni)
      acc[mi][ni] = (f32x4){0.f, 0.f, 0.f, 0.f};

#pragma unroll
  for (int kc = 0; kc < 4; ++kc) {
#pragma unroll
    for (int ks = 0; ks < 2; ++ks) {
      const int ko = (kc << 6) + (ks << 5) + (q << 3);
      short8 af[4], bfr[4];
#pragma unroll
      for (int mi = 0; mi < 4; ++mi)
        af[mi] = *(const short8*)(hbf + (((size_t)(m0 + mi * 16 + r)) << 8) + ko);
      const size_t wb = ((size_t)(((((g << 2) + kc) << 2) + w) * 2 + ks)) << 11;  // <<8 frag-groups, x8 shorts
#pragma unroll
      for (int ni = 0; ni < 4; ++ni)
        bfr[ni] = *(const short8*)(Wt + wb + (((ni << 6) + lane) << 3));
#pragma unroll
      for (int mi = 0; mi < 4; ++mi)
#pragma unroll
        for (int ni = 0; ni < 4; ++ni)
          acc[mi][ni] = __builtin_amdgcn_mfma_f32_16x16x32_bf16(af[mi], bfr[ni], acc[mi][ni], 0, 0, 0);
    }
  }

#pragma unroll
  for (int ni = 0; ni < 4; ++ni) {
    int n = (w << 6) + ni * 16 + r;
    float bmn = bm[n];
#pragma unroll
    for (int mi = 0; mi < 4; ++mi)
#pragma unroll
      for (int reg = 0; reg < 4; ++reg) {
        size_t idx = (((size_t)(m0 + mi * 16 + q * 4 + reg)) << 8) + n;
        float v = acc[mi][ni][reg];
        if (g == 0) X[idx]  = f2bf(v);
        else        Zb[idx] = f2bf(v + bmn);
      }
  }
}

// ---------------- edge kernel: per-node segments, zero atomics, butterfly OUT of loop ----------------
// m_e = relu(X[src] + Zb[n] + d_e*wl); agg[n] = sum m_e (bf16);
// pd partials accumulated PER-LANE with unreduced cp; one 3-component butterfly per node.
__launch_bounds__(256)
__global__ void edge_kernel(const unsigned short* __restrict__ X,
                            const unsigned short* __restrict__ Zb,
                            const float* __restrict__ pos_c,
                            const int* __restrict__ rowptr, const int* __restrict__ src_s,
                            const float* __restrict__ wl, const float* __restrict__ wp,
                            unsigned short* __restrict__ aggb, float* __restrict__ pos_o) {
  const int gid = blockIdx.x * 256 + threadIdx.x;
  const int wave = gid >> 6;
  const int lane = threadIdx.x & 63;

  const float4 wlv = *(const float4*)(wl + (lane << 2));
  const float4 wpv = *(const float4*)(wp + (lane << 2));

#pragma unroll
  for (int ni = 0; ni < 4; ++ni) {
    const int n = (wave << 2) + ni;
    const int e0 = rowptr[n];
    const int e1 = (n == NN_ - 1) ? E_ : rowptr[n + 1];
    const ushort4 zv = *(const ushort4*)(Zb + (((size_t)n) << 8) + (lane << 2));
    const float z0 = bf2f(zv.x), z1 = bf2f(zv.y), z2 = bf2f(zv.z), z3 = bf2f(zv.w);
    const float pnx = pos_c[n * 3 + 0];
    const float pny = pos_c[n * 3 + 1];
    const float pnz = pos_c[n * 3 + 2];
    float a0 = 0.f, a1 = 0.f, a2 = 0.f, a3 = 0.f;
    float pdx = 0.f, pdy = 0.f, pdz = 0.f;     // per-lane partials (cp unreduced)
    for (int e = e0; e < e1; ++e) {
      const int s = src_s[e];
      const float dx = pnx - pos_c[s * 3 + 0];
      const float dy = pny - pos_c[s * 3 + 1];
      const float dz = pnz - pos_c[s * 3 + 2];
      const float d = sqrtf(dx * dx + dy * dy + dz * dz + 1e-12f);
      const ushort4 xv = *(const ushort4*)(X + (((size_t)s) << 8) + (lane << 2));
      const float v0 = fmaxf(bf2f(xv.x) + z0 + d * wlv.x, 0.f);
      const float v1 = fmaxf(bf2f(xv.y) + z1 + d * wlv.y, 0.f);
      const float v2 = fmaxf(bf2f(xv.z) + z2 + d * wlv.z, 0.f);
      const float v3 = fmaxf(bf2f(xv.w) + z3 + d * wlv.w, 0.f);
      a0 += v0; a1 += v1; a2 += v2; a3 += v3;
      const float cp = v0 * wpv.x + v1 * wpv.y + v2 * wpv.z + v3 * wpv.w;  // lane partial
      pdx += dx * cp; pdy += dy * cp; pdz += dz * cp;
    }
    ushort4 av;
    av.x = f2bf(a0); av.y = f2bf(a1); av.z = f2bf(a2); av.w = f2bf(a3);
    *(ushort4*)(aggb + (((size_t)n) << 8) + (lane << 2)) = av;
    // single cross-lane reduction per node (3 independent chains)
#pragma unroll
    for (int m = 1; m < 64; m <<= 1) {
      pdx += __shfl_xor(pdx, m, 64);
      pdy += __shfl_xor(pdy, m, 64);
      pdz += __shfl_xor(pdz, m, 64);
    }
    if (lane == 0) {
      pos_o[n * 3 + 0] = pnx + pdx * 0.25f;
      pos_o[n * 3 + 1] = pny + pdy * 0.25f;
      pos_o[n * 3 + 2] = pnz + pdz * 0.25f;
    }
  }
}

// ---------------- GEMM2 (LDS-free node update): h += relu([hbf|aggb]@Wu + bu); hbf = bf16(h) ----------------
__launch_bounds__(256)
__global__ void upd2_mfma(float* __restrict__ h, unsigned short* __restrict__ hbf,
                          const unsigned short* __restrict__ aggb,
                          const unsigned short* __restrict__ Wt,   // frag-order [8][4][2][4][64]x8
                          const float* __restrict__ bu) {
  const int t = threadIdx.x;
  const int m0 = blockIdx.x << 6;
  const int w = t >> 6;
  const int lane = t & 63;
  const int q = lane >> 4;
  const int r = lane & 15;

  f32x4 acc[4][4];
#pragma unroll
  for (int mi = 0; mi < 4; ++mi)
#pragma unroll
    for (int ni = 0; ni < 4; ++ni)
      acc[mi][ni] = (f32x4){0.f, 0.f, 0.f, 0.f};

#pragma unroll
  for (int kc = 0; kc < 8; ++kc) {
    const unsigned short* Abase = ((kc < 4) ? hbf : aggb) + ((kc & 3) << 6);
#pragma unroll
    for (int ks = 0; ks < 2; ++ks) {
      const int ko = (ks << 5) + (q << 3);
      short8 af[4], bfr[4];
#pragma unroll
      for (int mi = 0; mi < 4; ++mi)
        af[mi] = *(const short8*)(Abase + (((size_t)(m0 + mi * 16 + r)) << 8) + ko);
      const size_t wb = ((size_t)((((kc << 2) + w) << 1) + ks)) << 11;
#pragma unroll
      for (int ni = 0; ni < 4; ++ni)
        bfr[ni] = *(const short8*)(Wt + wb + (((ni << 6) + lane) << 3));
#pragma unroll
      for (int mi = 0; mi < 4; ++mi)
#pragma unroll
        for (int ni = 0; ni < 4; ++ni)
          acc[mi][ni] = __builtin_amdgcn_mfma_f32_16x16x32_bf16(af[mi], bfr[ni], acc[mi][ni], 0, 0, 0);
    }
  }

#pragma unroll
  for (int ni = 0; ni < 4; ++ni) {
    int n = (w << 6) + ni * 16 + r;
    float buv = bu[n];
#pragma unroll
    for (int mi = 0; mi < 4; ++mi)
#pragma unroll
      for (int reg = 0; reg < 4; ++reg) {
        size_t idx = (((size_t)(m0 + mi * 16 + q * 4 + reg)) << 8) + n;
        float v = h[idx] + fmaxf(acc[mi][ni][reg] + buv, 0.f);
        h[idx] = v;
        hbf[idx] = f2bf(v);
      }
  }
}

// ---------------- launcher ----------------

extern "C" void kernel_launch(void* const* d_in, const int* in_sizes, int n_in,
                              void* d_out, int out_size, void* d_ws, size_t ws_size,
                              hipStream_t stream) {
  const float* x         = (const float*)d_in[0];
  const float* positions = (const float*)d_in[1];
  const float* W_in      = (const float*)d_in[2];
  const float* b_in      = (const float*)d_in[3];
  const float* Wg1       = (const float*)d_in[4];
  const float* bg1       = (const float*)d_in[5];
  const float* Wg2       = (const float*)d_in[6];
  const float* bg2       = (const float*)d_in[7];
  const float* Wm        = (const float*)d_in[8];
  const float* bm        = (const float*)d_in[9];
  const float* Wu        = (const float*)d_in[10];
  const float* bu        = (const float*)d_in[11];
  const float* Wp        = (const float*)d_in[12];
  const float* W_out     = (const float*)d_in[13];
  const float* b_out     = (const float*)d_in[14];
  const int*   ei        = (const int*)d_in[15];
  float* out = (float*)d_out;

  // workspace layout — non-overlapping
  char* ws = (char*)d_ws;
  float*          h     = (float*)(ws);                          //   0        .. 64 MB
  unsigned short* hbf   = (unsigned short*)(ws +  67108864UL);   //  64 MB     .. 96 MB
  unsigned short* X     = (unsigned short*)(ws + 100663296UL);   //  96 MB     .. 128 MB
  unsigned short* Zb    = (unsigned short*)(ws + 134217728UL);   // 128 MB     .. 160 MB
  unsigned short* aggb  = (unsigned short*)(ws + 167772160UL);   // 160 MB     .. 192 MB
  float*          posA  = (float*)(ws + 201326592UL);            // +768 KB
  float*          posB  = (float*)(ws + 202113024UL);            // +768 KB
  float*          g     = (float*)(ws + 202899456UL);            // +2 MB
  float*          h0    = (float*)(ws + 204996608UL);            // +32 KB
  float*          md    = (float*)(ws + 205029376UL);            // +8 KB
  unsigned short* Wt1   = (unsigned short*)(ws + 205037568UL);   // +512 KB (2 layers, frag-order)
  unsigned short* Wut   = (unsigned short*)(ws + 205561856UL);   // +512 KB (2 layers, frag-order)
  int*            deg   = (int*)(ws + 206086144UL);              // +256 KB
  int*            cur   = (int*)(ws + 206348288UL);              // +256 KB
  int*            bsum  = (int*)(ws + 206610432UL);              // +1 KB
  int*            rowptr= (int*)(ws + 206611456UL);              // +256 KB -> ends 206873600
  int*            src_s = (int*)(ws + 206873600UL);              // +1 MB   -> ends 207922176

  // ---- CSR (counting sort by dst) ----
  hipMemsetAsync(deg, 0, (size_t)NN_ * sizeof(int), stream);
  deg_kernel<<<E_ / 256, 256, 0, stream>>>(ei, deg);
  scan1_kernel<<<256, 256, 0, stream>>>(deg, bsum);
  scan2_kernel<<<1, 256, 0, stream>>>(bsum);
  scan3_kernel<<<256, 256, 0, stream>>>(deg, bsum, cur);
  hipMemcpyAsync(rowptr, cur, (size_t)NN_ * sizeof(int), hipMemcpyDeviceToDevice, stream);
  scatter_kernel<<<E_ / 256, 256, 0, stream>>>(ei, cur, src_s);

  // ---- weight conversion (frag-order) ----
  for (int l = 0; l < L_; ++l) {
    wconvM_kernel<<<64, 256, 0, stream>>>(Wm + (size_t)l * 513 * H_, Wt1 + (size_t)l * 131072);
    wconvU_kernel<<<64, 256, 0, stream>>>(Wu + (size_t)l * 512 * H_, Wut + (size_t)l * 131072);
  }

  // ---- node/pos init ----
  h0_kernel<<<B_, 256, 0, stream>>>(x, W_in, b_in, h0);
  meand_kernel<<<N_, 256, 0, stream>>>(positions, md);
  g_kernel<<<N_, 256, 0, stream>>>(md, Wg1, bg1, Wg2, bg2, g);
  hinit_kernel<<<NN_ * 64 / 256, 256, 0, stream>>>(h0, g, h);
  posinit_kernel<<<NN_ * 3 / 256, 256, 0, stream>>>(positions, posA);
  hbf_kernel<<<NN_ * H_ / 8 / 256, 256, 0, stream>>>(h, hbf);

  float* pos_cur = posA;
  float* pos_nxt = posB;
  for (int l = 0; l < L_; ++l) {
    gemm1_mfma<<<dim3(NN_ / 64, 2), 256, 0, stream>>>(hbf, Wt1 + (size_t)l * 131072,
                                                      bm + (size_t)l * H_, X, Zb);
    edge_kernel<<<NN_ / 4 / 4, 256, 0, stream>>>(X, Zb, pos_cur, rowptr, src_s,
                                                 Wm + (size_t)l * 513 * H_ + 512 * H_,
                                                 Wp + (size_t)l * H_, aggb, pos_nxt);
    upd2_mfma<<<NN_ / 64, 256, 0, stream>>>(h, hbf, aggb, Wut + (size_t)l * 131072,
                                            bu + (size_t)l * H_);
    float* tmp = pos_cur; pos_cur = pos_nxt; pos_nxt = tmp;
  }

  out_kernel<<<NN_ * 64 / 256, 256, 0, stream>>>(h, W_out, b_out, out);
}

// Round 7
// 486.794 us; speedup vs baseline: 1.2323x; 1.2323x over previous
//
#include <hip/hip_runtime.h>
#include <math.h>

#define B_ 32
#define F_ 128
#define H_ 256
#define N_ 2048
#define L_ 2
#define E_ 262144
#define NN_ 65536          // B_*N_
// DEG = E/(B*N) = 4

typedef __attribute__((ext_vector_type(8))) short short8;   // 8 bf16 = 4 VGPRs (MFMA A/B frag)
typedef __attribute__((ext_vector_type(4))) float f32x4;    // MFMA C/D frag

static __device__ __forceinline__ unsigned short f2bf(float f) {
  unsigned int u = __float_as_uint(f);
  u += 0x7FFF + ((u >> 16) & 1);      // round-to-nearest-even
  return (unsigned short)(u >> 16);
}
static __device__ __forceinline__ float bf2f(unsigned short u) {
  return __uint_as_float(((unsigned int)u) << 16);
}

// ---------------- small kernels ----------------

__global__ void h0_kernel(const float* __restrict__ x, const float* __restrict__ W_in,
                          const float* __restrict__ b_in, float* __restrict__ h0) {
  int b = blockIdx.x;
  int j = threadIdx.x;
  float acc = b_in[j];
#pragma unroll 8
  for (int k = 0; k < F_; ++k)
    acc += x[b * F_ + k] * W_in[k * H_ + j];
  h0[b * H_ + j] = acc;
}

__global__ void meand_kernel(const float* __restrict__ positions, float* __restrict__ mean_d) {
  __shared__ float red[256];
  int i = blockIdx.x;
  int t = threadIdx.x;
  float px = positions[i * 3 + 0], py = positions[i * 3 + 1], pz = positions[i * 3 + 2];
  float s = 0.f;
  for (int j = t; j < N_; j += 256) {
    float dx = px - positions[j * 3 + 0];
    float dy = py - positions[j * 3 + 1];
    float dz = pz - positions[j * 3 + 2];
    s += sqrtf(dx * dx + dy * dy + dz * dz);
  }
  red[t] = s;
  __syncthreads();
  for (int off = 128; off > 0; off >>= 1) {
    if (t < off) red[t] += red[t + off];
    __syncthreads();
  }
  if (t == 0) mean_d[i] = red[0] / (float)(N_ - 1);
}

__global__ void g_kernel(const float* __restrict__ mean_d,
                         const float* __restrict__ Wg1, const float* __restrict__ bg1,
                         const float* __restrict__ Wg2, const float* __restrict__ bg2,
                         float* __restrict__ g) {
  __shared__ float hid[128];
  int n = blockIdx.x;
  int t = threadIdx.x;
  float md = mean_d[n];
  if (t < 128) {
    float w = Wg1[t] + Wg1[128 + t] + Wg1[256 + t];
    hid[t] = fmaxf(md * w + bg1[t], 0.f);
  }
  __syncthreads();
  float acc = bg2[t];
#pragma unroll 8
  for (int k = 0; k < 128; ++k)
    acc += hid[k] * Wg2[k * H_ + t];
  g[n * H_ + t] = acc;
}

__global__ void hinit_kernel(const float* __restrict__ h0, const float* __restrict__ g,
                             float* __restrict__ h) {
  int idx = blockIdx.x * blockDim.x + threadIdx.x;
  int row = idx >> 6;
  int c4 = (idx & 63) << 2;
  const float4 a = *(const float4*)(h0 + (row >> 11) * H_ + c4);
  const float4 b = *(const float4*)(g + (row & (N_ - 1)) * H_ + c4);
  float4 r;
  r.x = a.x + b.x; r.y = a.y + b.y; r.z = a.z + b.z; r.w = a.w + b.w;
  *(float4*)(h + row * H_ + c4) = r;
}

__global__ void posinit_kernel(const float* __restrict__ positions, float* __restrict__ pos) {
  int i = blockIdx.x * blockDim.x + threadIdx.x;
  int row = i / 3;
  int c = i - row * 3;
  pos[i] = positions[(row & (N_ - 1)) * 3 + c];
}

__global__ void out_kernel(const float* __restrict__ h, const float* __restrict__ Wout,
                           const float* __restrict__ bout, float* __restrict__ out) {
  int gid = blockIdx.x * blockDim.x + threadIdx.x;
  int node = gid >> 6;
  int lane = gid & 63;
  const float4 hv = *(const float4*)(h + node * H_ + (lane << 2));
  const float4 wv = *(const float4*)(Wout + (lane << 2));
  float p = hv.x * wv.x + hv.y * wv.y + hv.z * wv.z + hv.w * wv.w;
#pragma unroll
  for (int m = 1; m < 64; m <<= 1) p += __shfl_xor(p, m, 64);
  if (lane == 0) out[node] = p + bout[0];
}

// ---------------- CSR build (counting sort of edges by dst) ----------------

__global__ void deg_kernel(const int* __restrict__ ei, int* __restrict__ deg) {
  int e = blockIdx.x * 256 + threadIdx.x;
  atomicAdd(&deg[ei[E_ + e]], 1);
}

__global__ void scan1_kernel(const int* __restrict__ deg, int* __restrict__ bsum) {
  __shared__ int red[256];
  int t = threadIdx.x;
  red[t] = deg[blockIdx.x * 256 + t];
  __syncthreads();
  for (int off = 128; off > 0; off >>= 1) {
    if (t < off) red[t] += red[t + off];
    __syncthreads();
  }
  if (t == 0) bsum[blockIdx.x] = red[0];
}

__global__ void scan2_kernel(int* __restrict__ bsum) {
  __shared__ int s[256];
  int t = threadIdx.x;
  s[t] = bsum[t];
  __syncthreads();
  for (int off = 1; off < 256; off <<= 1) {
    int v = (t >= off) ? s[t - off] : 0;
    __syncthreads();
    s[t] += v;
    __syncthreads();
  }
  bsum[t] = (t == 0) ? 0 : s[t - 1];
}

__global__ void scan3_kernel(const int* __restrict__ deg, const int* __restrict__ bsum,
                             int* __restrict__ cur) {
  __shared__ int s[256];
  int t = threadIdx.x;
  int i = blockIdx.x * 256 + t;
  s[t] = deg[i];
  __syncthreads();
  for (int off = 1; off < 256; off <<= 1) {
    int v = (t >= off) ? s[t - off] : 0;
    __syncthreads();
    s[t] += v;
    __syncthreads();
  }
  int excl = (t == 0) ? 0 : s[t - 1];
  cur[i] = bsum[blockIdx.x] + excl;
}

// scatter src indices into dst-sorted order
__global__ void scatter_kernel(const int* __restrict__ ei, int* __restrict__ cur,
                               int* __restrict__ src_s) {
  int e = blockIdx.x * 256 + threadIdx.x;
  int s = ei[e], d = ei[E_ + e];
  int p = atomicAdd(&cur[d], 1);
  src_s[p] = s;
}

// ---------------- weight conversion ----------------

// Wm[l] top/bot halves -> Wt1 [2][4][256 n][64 kl] bf16 per layer
__global__ void wconv1_kernel(const float* __restrict__ Wm, unsigned short* __restrict__ Wt) {
  int idx = blockIdx.x * 256 + threadIdx.x;   // 131072
  int g = idx >> 16;
  int rem = idx & 65535;
  int kc = rem >> 14;
  int n = (rem >> 6) & 255;
  int kl = rem & 63;
  Wt[idx] = f2bf(Wm[(g * 256 + kc * 64 + kl) * H_ + n]);
}

// Wu [512][256] fp32 row-major -> [8][256 n][64 kl] bf16
__global__ void wconv_kernel(const float* __restrict__ W, unsigned short* __restrict__ Wt) {
  int idx = blockIdx.x * blockDim.x + threadIdx.x;   // 131072
  int kc = idx >> 14;
  int rem = idx & 16383;
  int n = rem >> 6;
  int kl = rem & 63;
  Wt[idx] = f2bf(W[(kc * 64 + kl) * H_ + n]);
}

__global__ void hbf_kernel(const float* __restrict__ h, unsigned short* __restrict__ hbf) {
  int i = (blockIdx.x * blockDim.x + threadIdx.x) << 3;
  const float4 a = *(const float4*)(h + i);
  const float4 b = *(const float4*)(h + i + 4);
  short8 v;
  v[0] = (short)f2bf(a.x); v[1] = (short)f2bf(a.y);
  v[2] = (short)f2bf(a.z); v[3] = (short)f2bf(a.w);
  v[4] = (short)f2bf(b.x); v[5] = (short)f2bf(b.y);
  v[6] = (short)f2bf(b.z); v[7] = (short)f2bf(b.w);
  *(short8*)(hbf + i) = v;
}

// ---------------- GEMM1: X = hbf@WmTop (bf16), Zb = hbf@WmBot + bm (bf16) ----------------
// grid (NN/64, 2): y=0 -> X, y=1 -> Zb. 64 rows x 256 cols per block, K=256 (4 chunks).
__launch_bounds__(256)
__global__ void gemm1_mfma(const unsigned short* __restrict__ hbf,
                           const unsigned short* __restrict__ Wt,   // [2][4][256][64]
                           const float* __restrict__ bm,
                           unsigned short* __restrict__ X, unsigned short* __restrict__ Zb) {
  __shared__ __align__(16) unsigned short sW[256 * 72];
  __shared__ __align__(16) unsigned short sA[64 * 72];

  const int t = threadIdx.x;
  const int m0 = blockIdx.x << 6;
  const int g = blockIdx.y;
  const int w = t >> 6;
  const int lane = t & 63;
  const int q = lane >> 4;
  const int r = lane & 15;
  const int eA = t >> 2;
  const int jA = t & 3;

  f32x4 acc[4][4];
#pragma unroll
  for (int mi = 0; mi < 4; ++mi)
#pragma unroll
    for (int ni = 0; ni < 4; ++ni)
      acc[mi][ni] = (f32x4){0.f, 0.f, 0.f, 0.f};

  for (int kc = 0; kc < 4; ++kc) {
    {
      const unsigned short* src = hbf + (((size_t)(m0 + eA)) << 8) + (kc << 6) + (jA << 4);
      unsigned short* dstp = sA + eA * 72 + (jA << 4);
      *(short8*)(dstp) = *(const short8*)(src);
      *(short8*)(dstp + 8) = *(const short8*)(src + 8);
    }
    {
      const unsigned short* src = Wt + (((size_t)((g << 2) + kc)) << 14) + (t << 3);
      const int nb = t >> 3;
      const int kb = (t & 7) << 3;
#pragma unroll
      for (int i = 0; i < 8; ++i) {
        short8 v = *(const short8*)(src + (i << 11));
        *(short8*)(sW + ((i << 5) + nb) * 72 + kb) = v;
      }
    }
    __syncthreads();
#pragma unroll
    for (int ks = 0; ks < 2; ++ks) {
      const int ko = (ks << 5) + (q << 3);
      short8 af[4], bfr[4];
#pragma unroll
      for (int mi = 0; mi < 4; ++mi)
        af[mi] = *(const short8*)(sA + (mi * 16 + r) * 72 + ko);
#pragma unroll
      for (int ni = 0; ni < 4; ++ni)
        bfr[ni] = *(const short8*)(sW + ((w << 6) + ni * 16 + r) * 72 + ko);
#pragma unroll
      for (int mi = 0; mi < 4; ++mi)
#pragma unroll
        for (int ni = 0; ni < 4; ++ni)
          acc[mi][ni] = __builtin_amdgcn_mfma_f32_16x16x32_bf16(af[mi], bfr[ni], acc[mi][ni], 0, 0, 0);
    }
    __syncthreads();
  }

#pragma unroll
  for (int ni = 0; ni < 4; ++ni) {
    int n = (w << 6) + ni * 16 + r;
    float bmn = bm[n];
#pragma unroll
    for (int mi = 0; mi < 4; ++mi)
#pragma unroll
      for (int reg = 0; reg < 4; ++reg) {
        size_t idx = (((size_t)(m0 + mi * 16 + q * 4 + reg)) << 8) + n;
        float v = acc[mi][ni][reg];
        if (g == 0) X[idx]  = f2bf(v);
        else        Zb[idx] = f2bf(v + bmn);
      }
  }
}

// ---------------- edge kernel: per-node segments, zero atomics, butterfly OUT of loop ----------------
// m_e = relu(X[src] + Zb[n] + d_e*wl); agg[n] = sum m_e (bf16);
// pd partials accumulated PER-LANE with unreduced cp; one 3-component butterfly per node.
__launch_bounds__(256)
__global__ void edge_kernel(const unsigned short* __restrict__ X,
                            const unsigned short* __restrict__ Zb,
                            const float* __restrict__ pos_c,
                            const int* __restrict__ rowptr, const int* __restrict__ src_s,
                            const float* __restrict__ wl, const float* __restrict__ wp,
                            unsigned short* __restrict__ aggb, float* __restrict__ pos_o) {
  const int gid = blockIdx.x * 256 + threadIdx.x;
  const int wave = gid >> 6;
  const int lane = threadIdx.x & 63;

  const float4 wlv = *(const float4*)(wl + (lane << 2));
  const float4 wpv = *(const float4*)(wp + (lane << 2));

#pragma unroll
  for (int ni = 0; ni < 4; ++ni) {
    const int n = (wave << 2) + ni;
    const int e0 = rowptr[n];
    const int e1 = (n == NN_ - 1) ? E_ : rowptr[n + 1];
    const ushort4 zv = *(const ushort4*)(Zb + (((size_t)n) << 8) + (lane << 2));
    const float z0 = bf2f(zv.x), z1 = bf2f(zv.y), z2 = bf2f(zv.z), z3 = bf2f(zv.w);
    const float pnx = pos_c[n * 3 + 0];
    const float pny = pos_c[n * 3 + 1];
    const float pnz = pos_c[n * 3 + 2];
    float a0 = 0.f, a1 = 0.f, a2 = 0.f, a3 = 0.f;
    float pdx = 0.f, pdy = 0.f, pdz = 0.f;     // per-lane partials (cp unreduced)
    for (int e = e0; e < e1; ++e) {
      const int s = src_s[e];
      const float dx = pnx - pos_c[s * 3 + 0];
      const float dy = pny - pos_c[s * 3 + 1];
      const float dz = pnz - pos_c[s * 3 + 2];
      const float d = sqrtf(dx * dx + dy * dy + dz * dz + 1e-12f);
      const ushort4 xv = *(const ushort4*)(X + (((size_t)s) << 8) + (lane << 2));
      const float v0 = fmaxf(bf2f(xv.x) + z0 + d * wlv.x, 0.f);
      const float v1 = fmaxf(bf2f(xv.y) + z1 + d * wlv.y, 0.f);
      const float v2 = fmaxf(bf2f(xv.z) + z2 + d * wlv.z, 0.f);
      const float v3 = fmaxf(bf2f(xv.w) + z3 + d * wlv.w, 0.f);
      a0 += v0; a1 += v1; a2 += v2; a3 += v3;
      const float cp = v0 * wpv.x + v1 * wpv.y + v2 * wpv.z + v3 * wpv.w;  // lane partial
      pdx += dx * cp; pdy += dy * cp; pdz += dz * cp;
    }
    ushort4 av;
    av.x = f2bf(a0); av.y = f2bf(a1); av.z = f2bf(a2); av.w = f2bf(a3);
    *(ushort4*)(aggb + (((size_t)n) << 8) + (lane << 2)) = av;
    // single cross-lane reduction per node (3 independent chains)
#pragma unroll
    for (int m = 1; m < 64; m <<= 1) {
      pdx += __shfl_xor(pdx, m, 64);
      pdy += __shfl_xor(pdy, m, 64);
      pdz += __shfl_xor(pdz, m, 64);
    }
    if (lane == 0) {
      pos_o[n * 3 + 0] = pnx + pdx * 0.25f;
      pos_o[n * 3 + 1] = pny + pdy * 0.25f;
      pos_o[n * 3 + 2] = pnz + pdz * 0.25f;
    }
  }
}

// ---------------- GEMM2 (node update): h += relu([hbf|aggb]@Wu + bu); hbf = bf16(h) ----------------
__launch_bounds__(256)
__global__ void upd2_mfma(float* __restrict__ h, unsigned short* __restrict__ hbf,
                          const unsigned short* __restrict__ aggb,
                          const unsigned short* __restrict__ Wt,   // [8][256][64] bf16
                          const float* __restrict__ bu) {
  __shared__ __align__(16) unsigned short sW[256 * 72];
  __shared__ __align__(16) unsigned short sA[64 * 72];

  const int t = threadIdx.x;
  const int m0 = blockIdx.x << 6;
  const int w = t >> 6;
  const int lane = t & 63;
  const int q = lane >> 4;
  const int r = lane & 15;
  const int eA = t >> 2;
  const int jA = t & 3;

  f32x4 acc[4][4];
#pragma unroll
  for (int mi = 0; mi < 4; ++mi)
#pragma unroll
    for (int ni = 0; ni < 4; ++ni)
      acc[mi][ni] = (f32x4){0.f, 0.f, 0.f, 0.f};

  for (int kc = 0; kc < 8; ++kc) {
    {
      const unsigned short* base = (kc < 4) ? hbf : aggb;
      const unsigned short* src = base + (((size_t)(m0 + eA)) << 8) + ((kc & 3) << 6) + (jA << 4);
      unsigned short* dstp = sA + eA * 72 + (jA << 4);
      *(short8*)(dstp) = *(const short8*)(src);
      *(short8*)(dstp + 8) = *(const short8*)(src + 8);
    }
    {
      const unsigned short* src = Wt + (((size_t)kc) << 14) + (t << 3);
      const int nb = t >> 3;
      const int kb = (t & 7) << 3;
#pragma unroll
      for (int i = 0; i < 8; ++i) {
        short8 v = *(const short8*)(src + (i << 11));
        *(short8*)(sW + ((i << 5) + nb) * 72 + kb) = v;
      }
    }
    __syncthreads();
#pragma unroll
    for (int ks = 0; ks < 2; ++ks) {
      const int ko = (ks << 5) + (q << 3);
      short8 af[4], bfr[4];
#pragma unroll
      for (int mi = 0; mi < 4; ++mi)
        af[mi] = *(const short8*)(sA + (mi * 16 + r) * 72 + ko);
#pragma unroll
      for (int ni = 0; ni < 4; ++ni)
        bfr[ni] = *(const short8*)(sW + ((w << 6) + ni * 16 + r) * 72 + ko);
#pragma unroll
      for (int mi = 0; mi < 4; ++mi)
#pragma unroll
        for (int ni = 0; ni < 4; ++ni)
          acc[mi][ni] = __builtin_amdgcn_mfma_f32_16x16x32_bf16(af[mi], bfr[ni], acc[mi][ni], 0, 0, 0);
    }
    __syncthreads();
  }

#pragma unroll
  for (int ni = 0; ni < 4; ++ni) {
    int n = (w << 6) + ni * 16 + r;
    float buv = bu[n];
#pragma unroll
    for (int mi = 0; mi < 4; ++mi)
#pragma unroll
      for (int reg = 0; reg < 4; ++reg) {
        size_t idx = (((size_t)(m0 + mi * 16 + q * 4 + reg)) << 8) + n;
        float v = h[idx] + fmaxf(acc[mi][ni][reg] + buv, 0.f);
        h[idx] = v;
        hbf[idx] = f2bf(v);
      }
  }
}

// ---------------- launcher ----------------

extern "C" void kernel_launch(void* const* d_in, const int* in_sizes, int n_in,
                              void* d_out, int out_size, void* d_ws, size_t ws_size,
                              hipStream_t stream) {
  const float* x         = (const float*)d_in[0];
  const float* positions = (const float*)d_in[1];
  const float* W_in      = (const float*)d_in[2];
  const float* b_in      = (const float*)d_in[3];
  const float* Wg1       = (const float*)d_in[4];
  const float* bg1       = (const float*)d_in[5];
  const float* Wg2       = (const float*)d_in[6];
  const float* bg2       = (const float*)d_in[7];
  const float* Wm        = (const float*)d_in[8];
  const float* bm        = (const float*)d_in[9];
  const float* Wu        = (const float*)d_in[10];
  const float* bu        = (const float*)d_in[11];
  const float* Wp        = (const float*)d_in[12];
  const float* W_out     = (const float*)d_in[13];
  const float* b_out     = (const float*)d_in[14];
  const int*   ei        = (const int*)d_in[15];
  float* out = (float*)d_out;

  // workspace layout — non-overlapping
  char* ws = (char*)d_ws;
  float*          h     = (float*)(ws);                          //   0        .. 64 MB
  unsigned short* hbf   = (unsigned short*)(ws +  67108864UL);   //  64 MB     .. 96 MB
  unsigned short* X     = (unsigned short*)(ws + 100663296UL);   //  96 MB     .. 128 MB
  unsigned short* Zb    = (unsigned short*)(ws + 134217728UL);   // 128 MB     .. 160 MB
  unsigned short* aggb  = (unsigned short*)(ws + 167772160UL);   // 160 MB     .. 192 MB
  float*          posA  = (float*)(ws + 201326592UL);            // +768 KB
  float*          posB  = (float*)(ws + 202113024UL);            // +768 KB
  float*          g     = (float*)(ws + 202899456UL);            // +2 MB
  float*          h0    = (float*)(ws + 204996608UL);            // +32 KB
  float*          md    = (float*)(ws + 205029376UL);            // +8 KB
  unsigned short* Wt1   = (unsigned short*)(ws + 205037568UL);   // +512 KB (2 layers)
  unsigned short* Wut   = (unsigned short*)(ws + 205561856UL);   // +512 KB (2 layers)
  int*            deg   = (int*)(ws + 206086144UL);              // +256 KB
  int*            cur   = (int*)(ws + 206348288UL);              // +256 KB
  int*            bsum  = (int*)(ws + 206610432UL);              // +1 KB
  int*            rowptr= (int*)(ws + 206611456UL);              // +256 KB -> ends 206873600
  int*            src_s = (int*)(ws + 206873600UL);              // +1 MB   -> ends 207922176

  // ---- CSR (counting sort by dst) ----
  hipMemsetAsync(deg, 0, (size_t)NN_ * sizeof(int), stream);
  deg_kernel<<<E_ / 256, 256, 0, stream>>>(ei, deg);
  scan1_kernel<<<256, 256, 0, stream>>>(deg, bsum);
  scan2_kernel<<<1, 256, 0, stream>>>(bsum);
  scan3_kernel<<<256, 256, 0, stream>>>(deg, bsum, cur);
  hipMemcpyAsync(rowptr, cur, (size_t)NN_ * sizeof(int), hipMemcpyDeviceToDevice, stream);
  scatter_kernel<<<E_ / 256, 256, 0, stream>>>(ei, cur, src_s);

  // ---- weight conversion ----
  for (int l = 0; l < L_; ++l) {
    wconv1_kernel<<<512, 256, 0, stream>>>(Wm + (size_t)l * 513 * H_, Wt1 + (size_t)l * 131072);
    wconv_kernel<<<512, 256, 0, stream>>>(Wu + (size_t)l * 512 * H_, Wut + (size_t)l * 131072);
  }

  // ---- node/pos init ----
  h0_kernel<<<B_, 256, 0, stream>>>(x, W_in, b_in, h0);
  meand_kernel<<<N_, 256, 0, stream>>>(positions, md);
  g_kernel<<<N_, 256, 0, stream>>>(md, Wg1, bg1, Wg2, bg2, g);
  hinit_kernel<<<NN_ * 64 / 256, 256, 0, stream>>>(h0, g, h);
  posinit_kernel<<<NN_ * 3 / 256, 256, 0, stream>>>(positions, posA);
  hbf_kernel<<<NN_ * H_ / 8 / 256, 256, 0, stream>>>(h, hbf);

  float* pos_cur = posA;
  float* pos_nxt = posB;
  for (int l = 0; l < L_; ++l) {
    gemm1_mfma<<<dim3(NN_ / 64, 2), 256, 0, stream>>>(hbf, Wt1 + (size_t)l * 131072,
                                                      bm + (size_t)l * H_, X, Zb);
    edge_kernel<<<NN_ / 16, 256, 0, stream>>>(X, Zb, pos_cur, rowptr, src_s,
                                              Wm + (size_t)l * 513 * H_ + 512 * H_,
                                              Wp + (size_t)l * H_, aggb, pos_nxt);
    upd2_mfma<<<NN_ / 64, 256, 0, stream>>>(h, hbf, aggb, Wut + (size_t)l * 131072,
                                            bu + (size_t)l * H_);
    float* tmp = pos_cur; pos_cur = pos_nxt; pos_nxt = tmp;
  }

  out_kernel<<<NN_ * 64 / 256, 256, 0, stream>>>(h, W_out, b_out, out);
}